// Round 3
// baseline (143.167 us; speedup 1.0000x reference)
//
#include <hip/hip_runtime.h>
#include <stdint.h>

// ---------------- problem constants ----------------
#define NIMG   64
#define NCH    2048
#define HW7    49          // 7*7
#define OUTW   224
#define NPIX   50176       // 224*224 = 49*1024
#define CROP_N 9633792     // 64*3*224*224
#define HEAT_OFF  9633792
#define COORD_OFF 12845056 // CROP_N + 64*NPIX
#define THRESH 0.7f

#define MAXR 4             // max runs per row (piecewise-linear row over 6 cells -> <=4 runs)
#define RCAP (224*MAXR)    // 896 run slots per image
#define NWORDS 784         // 50176 bits / 64
#define WPAD   788         // padded: row extraction reads +4 words (zeroed in LDS)

#define NGRP 16            // k1 channel groups per image (1024 blocks total)

// scratch inside d_out's crop region (fully overwritten by k4 afterwards):
//   byte 0 : float heatPart[1024*49]  (200704 B)

// =====================================================================
// K1: heat partials. 1024 blocks = 16 channel-groups x 64 images.
// Wave-per-channel: lane l (<49) accumulates max|F| for pos l in registers.
// =====================================================================
__global__ __launch_bounds__(256) void k1_heat(const float* __restrict__ F,
                                               float* __restrict__ heatPart) {
    __shared__ float smax[4][64];
    const int t = threadIdx.x;
    const int b = blockIdx.x;
    const int n = b >> 4, g = b & 15;
    const int w = t >> 6, l = t & 63;
    const int lp = (l < HW7) ? l : 0;          // lanes >=49 re-read pos 0 (same cache lines)
    const float* base = F + (size_t)n * 100352 + (size_t)(g * 128 + w) * HW7 + lp;
    float vmax = 0.0f;
#pragma unroll 8
    for (int i = 0; i < 32; ++i) {
        vmax = fmaxf(vmax, fabsf(base[(size_t)i * 4 * HW7]));
    }
    smax[w][l] = vmax;
    __syncthreads();
    if (t < HW7) {
        float m = fmaxf(fmaxf(smax[0][t], smax[1][t]), fmaxf(smax[2][t], smax[3][t]));
        heatPart[b * HW7 + t] = m;
    }
}

// =====================================================================
// union-find helpers on LDS
// =====================================================================
__device__ inline unsigned uf_find(volatile unsigned* P, unsigned x) {
    while (true) {
        unsigned p = P[x];
        if (p == x) return x;
        unsigned gp = P[p];
        if (gp == p) return p;
        P[x] = gp;      // path halving: benign race, parent always decreases
        x = gp;
    }
}

__device__ inline void uf_merge(volatile unsigned* P, unsigned a, unsigned b) {
    while (true) {
        a = uf_find(P, a); b = uf_find(P, b);
        if (a == b) return;
        if (a > b) { unsigned tmp = a; a = b; b = tmp; }
        unsigned old = atomicCAS((unsigned*)&P[b], b, a);
        if (old == b) return;
        b = old;
    }
}

// =====================================================================
// K23: one block per image (1024 threads = 16 waves, 4 waves/SIMD).
// Phase A: reduce partials -> normalize -> bilinear upsample; store
// heatOut and ballot the threshold mask DIRECTLY INTO LDS (no global
// mask round-trip). Phase B: run-based CCL on the LDS mask + bbox.
// 50176 px = 49 iterations x 1024 threads exactly, no divergence.
// ~34 KB LDS.
// =====================================================================
__global__ __launch_bounds__(1024) void k23_heat_ccl(const float* __restrict__ heatPart,
                                                     float* __restrict__ heatOut,
                                                     float* __restrict__ coords) {
#pragma clang fp contract(off)
    // ---- phase A state
    __shared__ float raw[HW7];
    __shared__ float h7[HW7];
    __shared__ float s_mn, s_mx;
    __shared__ float wT[OUTW];      // fractional weight per output index
    __shared__ int   i0T[OUTW];     // low tap
    __shared__ int   i1T[OUTW];     // high tap
    // ---- mask + CCL state
    __shared__ unsigned long long W[WPAD];
    __shared__ unsigned short runS[RCAP], runE[RCAP];
    __shared__ unsigned char nRuns[224];
    __shared__ unsigned parent[RCAP], cnt[RCAP];
    __shared__ unsigned rmin[RCAP], rmax[RCAP], cmin[RCAP], cmax[RCAP];
    __shared__ unsigned bestScore, bestRid;

    const int t = threadIdx.x;
    const int n = blockIdx.x;

    // ---- init (overlapped): partial reduce, tap tables, CCL state, W pads
    if (t < HW7) {
        float m = heatPart[(n * NGRP + 0) * HW7 + t];
#pragma unroll
        for (int g = 1; g < NGRP; ++g) m = fmaxf(m, heatPart[(n * NGRP + g) * HW7 + t]);
        raw[t] = m;
    }
    if (t < OUTW) {
        // EXACT reference op order: g = i/223 ; s = g*6 ; floor/clip ; w = s - i0
        float gx = (float)t / 223.0f;
        float xs = gx * 6.0f;
        int x0 = (int)floorf(xs); x0 = min(max(x0, 0), 6);
        i0T[t] = x0;
        i1T[t] = min(x0 + 1, 6);
        wT[t]  = xs - (float)x0;
    }
    if (t < RCAP) {
        parent[t] = (unsigned)t; cnt[t] = 0u;
        rmin[t] = 0xFFFFFFFFu; rmax[t] = 0u; cmin[t] = 0xFFFFFFFFu; cmax[t] = 0u;
    }
    if (t >= NWORDS && t < WPAD) W[t] = 0ull;   // pad words
    if (t == 0) { bestScore = 0u; bestRid = 0u; }
    __syncthreads();
    if (t == 0) {
        float mn = raw[0], mx = raw[0];
        for (int i = 1; i < HW7; ++i) { float v = raw[i]; mn = fminf(mn, v); mx = fmaxf(mx, v); }
        s_mn = mn; s_mx = mx;
    }
    __syncthreads();
    if (t < HW7) h7[t] = (raw[t] - s_mn) / (s_mx - s_mn);
    __syncthreads();

    // ---- upsample: store heatOut (async drain) + ballot mask into LDS
    for (int k = 0; k < 49; ++k) {
        int p = (k << 10) + t;            // all 1024 threads active, p < 50176
        int i = p / 224, j = p - i * 224;
        int x0 = i0T[i], x1 = i1T[i];
        int y0 = i0T[j], y1 = i1T[j];
        float wx = wT[i], wy = wT[j];
        float v00 = h7[x0 * 7 + y0], v01 = h7[x0 * 7 + y1];
        float v10 = h7[x1 * 7 + y0], v11 = h7[x1 * 7 + y1];
        float val = (1.0f - wx) * ((1.0f - wy) * v00 + wy * v01)
                  + wx * ((1.0f - wy) * v10 + wy * v11);
        heatOut[(size_t)n * NPIX + p] = val;
        unsigned long long bal = __ballot(val > THRESH);
        if ((t & 63) == 0) W[p >> 6] = bal;   // wave-disjoint words, no race
    }
    __syncthreads();

    // ================= phase B: CCL on LDS mask =================
    // ---- run extraction: one thread per row, bit-trick start/end finding
    if (t < 224) {
        const int r = t;
        const int bit0 = r * 224;
        const int w0 = bit0 >> 6, sh = bit0 & 63;
        unsigned long long rb[4];
#pragma unroll
        for (int q = 0; q < 4; ++q) {
            unsigned long long lo = W[w0 + q] >> sh;
            unsigned long long hi = sh ? (W[w0 + q + 1] << (64 - sh)) : 0ull;
            rb[q] = lo | hi;
        }
        rb[3] &= 0xFFFFFFFFull;   // keep bits 192..223 only

        unsigned long long st[4], en[4];
        unsigned long long carry = 0ull;
#pragma unroll
        for (int q = 0; q < 4; ++q) {
            unsigned long long shl = (rb[q] << 1) | carry;
            carry = rb[q] >> 63;
            st[q] = rb[q] & ~shl;                         // run starts
        }
#pragma unroll
        for (int q = 0; q < 4; ++q) {
            unsigned long long nxt = (q < 3) ? rb[q + 1] : 0ull;
            en[q] = rb[q] & ~((rb[q] >> 1) | (nxt << 63)); // run ends
        }
        int ns = 0;
#pragma unroll
        for (int q = 0; q < 4; ++q) {
            unsigned long long x = st[q];
            while (x) {
                int z = __builtin_ctzll(x); x &= x - 1;
                if (ns < MAXR) runS[r * MAXR + ns] = (unsigned short)(q * 64 + z);
                ns++;
            }
        }
        int ne = 0;
#pragma unroll
        for (int q = 0; q < 4; ++q) {
            unsigned long long x = en[q];
            while (x) {
                int z = __builtin_ctzll(x); x &= x - 1;
                if (ne < MAXR) runE[r * MAXR + ne] = (unsigned short)(q * 64 + z);
                ne++;
            }
        }
        nRuns[r] = (unsigned char)min(ns, MAXR);
    }
    __syncthreads();

    // ---- union runs overlapping (8-connectivity) with previous row.
    // Parallel over (row, run): 896 threads, each <=4 overlap tests.
    if (t >= MAXR && t < RCAP) {           // rows 1..223
        const int r = t >> 2, k = t & (MAXR - 1);
        if (k < (int)nRuns[r]) {
            const int nb = nRuns[r - 1];
            int s = runS[t], e = runE[t];
            for (int m = 0; m < nb; ++m) {
                int qid = (r - 1) * MAXR + m;
                int s2 = runS[qid], e2 = runE[qid];
                if (s2 <= e + 1 && e2 >= s - 1) uf_merge(parent, (unsigned)t, (unsigned)qid);
            }
        }
    }
    __syncthreads();

    // ---- accumulate sizes + per-component bbox (1 iteration: RCAP < 1024)
    if (t < RCAP) {
        int r = t >> 2, k = t & (MAXR - 1);
        if (k < (int)nRuns[r]) {
            int s = runS[t], e = runE[t];
            unsigned root = uf_find(parent, (unsigned)t);
            atomicAdd(&cnt[root], (unsigned)(e - s + 1));
            atomicMin(&rmin[root], (unsigned)r);
            atomicMax(&rmax[root], (unsigned)r);
            atomicMin(&cmin[root], (unsigned)s);
            atomicMax(&cmax[root], (unsigned)e);
        }
    }
    __syncthreads();

    // ---- select: max count, tie -> min reference label (= min pixel index)
    if (t < RCAP) {
        unsigned c = cnt[t];
        if (c > 0u) {
            unsigned label = (unsigned)((t >> 2) * 224 + (int)runS[t]); // root = min (row,start)
            unsigned score = (c << 16) | (65535u - label);
            atomicMax(&bestScore, score);
        }
    }
    __syncthreads();
    if (t < RCAP) {
        unsigned c = cnt[t];
        if (c > 0u) {
            unsigned label = (unsigned)((t >> 2) * 224 + (int)runS[t]);
            unsigned score = (c << 16) | (65535u - label);
            if (score == bestScore) bestRid = (unsigned)t;  // unique writer
        }
    }
    __syncthreads();

    if (t == 0) {
        int xmin, xmax, ymin, ymax;
        if (bestScore == 0u) {           // empty mask -> reference fallback
            xmin = 0; ymin = 0; xmax = 223; ymax = 223;
        } else {
            unsigned rb_ = bestRid;
            xmin = (int)rmin[rb_]; xmax = (int)rmax[rb_];
            ymin = (int)cmin[rb_]; ymax = (int)cmax[rb_];
        }
        coords[n * 4 + 0] = (float)ymin;  // torch coord order [ymin,xmin,ymax,xmax]
        coords[n * 4 + 1] = (float)xmin;
        coords[n * 4 + 2] = (float)ymax;
        coords[n * 4 + 3] = (float)xmax;
    }
}

// =====================================================================
// K4: crop + bilinear resize. 4 pixels per thread (same output row:
// 224 % 4 == 0), so x-taps/wx are computed once per thread; stores are
// dwordx4. 3136 blocks = 49 per image. Memory-bound (~77 MB).
// =====================================================================
__global__ __launch_bounds__(256) void k4_crop(const float* __restrict__ X,
                                               const float* __restrict__ coords,
                                               float* __restrict__ out) {
#pragma clang fp contract(off)
    const int t = threadIdx.x;
    const int b = blockIdx.x;
    const int n = b / 49;                // uniform per block -> coords loads scalarize
    const int p4 = ((b % 49) * 256 + t) * 4;
    const int oi = p4 / 224, oj = p4 - oi * 224;   // oj..oj+3 in same row

    int ymin = (int)coords[n * 4 + 0];
    int xmin = (int)coords[n * 4 + 1];
    int ymax = (int)coords[n * 4 + 2];
    int xmax = (int)coords[n * 4 + 3];
    int Lx = max(xmax - xmin, 1);
    int Ly = max(ymax - ymin, 1);

    // x (row) taps: identical for all 4 pixels of this thread
    float gx = (float)oi / 223.0f;
    float xs = (float)xmin + gx * (float)(Lx - 1);
    int x0 = (int)floorf(xs); x0 = min(max(x0, 0), 223); int x1 = min(x0 + 1, 223);
    float wx = xs - (float)x0;

    int   y0q[4], y1q[4];
    float wyq[4];
#pragma unroll
    for (int q = 0; q < 4; ++q) {
        float gy = (float)(oj + q) / 223.0f;
        float ys = (float)ymin + gy * (float)(Ly - 1);
        int y0 = (int)floorf(ys); y0 = min(max(y0, 0), 223);
        y0q[q] = y0; y1q[q] = min(y0 + 1, 223);
        wyq[q] = ys - (float)y0;
    }

    const float* img = X + (size_t)n * 150528;
    float* obase = out + (size_t)n * 150528 + p4;
#pragma unroll
    for (int ch = 0; ch < 3; ++ch) {
        const float* rt = img + ch * NPIX + x0 * 224;
        const float* rb = img + ch * NPIX + x1 * 224;
        float r[4];
#pragma unroll
        for (int q = 0; q < 4; ++q) {
            float v00 = rt[y0q[q]], v01 = rt[y1q[q]];
            float v10 = rb[y0q[q]], v11 = rb[y1q[q]];
            r[q] = (1.0f - wx) * ((1.0f - wyq[q]) * v00 + wyq[q] * v01)
                 + wx * ((1.0f - wyq[q]) * v10 + wyq[q] * v11);
        }
        *reinterpret_cast<float4*>(obase + (size_t)ch * NPIX) =
            make_float4(r[0], r[1], r[2], r[3]);
    }
}

// =====================================================================
extern "C" void kernel_launch(void* const* d_in, const int* in_sizes, int n_in,
                              void* d_out, int out_size, void* d_ws, size_t ws_size,
                              hipStream_t stream) {
    (void)in_sizes; (void)n_in; (void)out_size; (void)d_ws; (void)ws_size;
    const float* X = (const float*)d_in[0];   // (64,3,224,224)
    const float* F = (const float*)d_in[1];   // (64,2048,7,7)
    float* out = (float*)d_out;

    float* heatPart = (float*)d_out;          // scratch in crop region
    float* heatOut = out + HEAT_OFF;
    float* coords  = out + COORD_OFF;

    k1_heat     <<<dim3(1024), dim3(256),  0, stream>>>(F, heatPart);
    k23_heat_ccl<<<dim3(64),   dim3(1024), 0, stream>>>(heatPart, heatOut, coords);
    k4_crop     <<<dim3(3136), dim3(256),  0, stream>>>(X, coords, out);
}

// Round 5
// 137.026 us; speedup vs baseline: 1.0448x; 1.0448x over previous
//
#include <hip/hip_runtime.h>
#include <stdint.h>

// ---------------- problem constants ----------------
#define NIMG   64
#define NCH    2048
#define HW7    49          // 7*7
#define OUTW   224
#define NPIX   50176       // 224*224
#define CROP_N 9633792     // 64*3*224*224
#define HEAT_OFF  9633792
#define COORD_OFF 12845056 // CROP_N + 64*NPIX
#define THRESH 0.7f

#define MAXR 4             // max runs per row (piecewise-linear row over 6 cells -> <=4 runs)
#define RCAP (224*MAXR)    // 896 run slots per image
#define NWORDS 784         // 50176 bits / 64
#define WPAD   788         // padded: row extraction reads +4 words (zeroed in LDS)

#define NGRP 16            // k1 channel groups per image (1024 blocks total)

// scratch inside d_out's crop region (fully overwritten by k4 afterwards):
//   byte 0      : float heatPart[1024*49]               (200704 B)
//   byte 262144 : unsigned long long maskW[64*784]      (401408 B) -> ends 663552
//   byte 663552 : unsigned imgCnt[64]                   (256 B)
#define MASKW_BYTE_OFF 262144
#define CNT_BYTE_OFF   663552

// =====================================================================
// K1: heat partials. 1024 blocks = 16 channel-groups x 64 images.
// Wave-per-channel: lane l (<49) accumulates max|F| for pos l in registers.
// Block 0 also zeroes the per-image arrival counters (agent-scope, so
// k23's agent-scope fetch_add RMWs the fresh value) — pattern validated
// in round 1.
// =====================================================================
__global__ __launch_bounds__(256) void k1_heat(const float* __restrict__ F,
                                               float* __restrict__ heatPart,
                                               unsigned* __restrict__ imgCnt) {
    __shared__ float smax[4][64];
    const int t = threadIdx.x;
    const int b = blockIdx.x;
    if (b == 0 && t < NIMG) {
        __hip_atomic_store(&imgCnt[t], 0u, __ATOMIC_RELAXED, __HIP_MEMORY_SCOPE_AGENT);
    }
    const int n = b >> 4, g = b & 15;
    const int w = t >> 6, l = t & 63;
    const int lp = (l < HW7) ? l : 0;          // lanes >=49 re-read pos 0 (same cache lines)
    const float* base = F + (size_t)n * 100352 + (size_t)(g * 128 + w) * HW7 + lp;
    float vmax = 0.0f;
#pragma unroll 8
    for (int i = 0; i < 32; ++i) {
        vmax = fmaxf(vmax, fabsf(base[(size_t)i * 4 * HW7]));
    }
    smax[w][l] = vmax;
    __syncthreads();
    if (t < HW7) {
        float m = fmaxf(fmaxf(smax[0][t], smax[1][t]), fmaxf(smax[2][t], smax[3][t]));
        heatPart[b * HW7 + t] = m;
    }
}

// =====================================================================
// union-find helpers on LDS
// =====================================================================
__device__ inline unsigned uf_find(volatile unsigned* P, unsigned x) {
    while (true) {
        unsigned p = P[x];
        if (p == x) return x;
        unsigned gp = P[p];
        if (gp == p) return p;
        P[x] = gp;      // path halving: benign race, parent always decreases
        x = gp;
    }
}

__device__ inline void uf_merge(volatile unsigned* P, unsigned a, unsigned b) {
    while (true) {
        a = uf_find(P, a); b = uf_find(P, b);
        if (a == b) return;
        if (a > b) { unsigned tmp = a; a = b; b = tmp; }
        unsigned old = atomicCAS((unsigned*)&P[b], b, a);
        if (old == b) return;
        b = old;
    }
}

// =====================================================================
// K23: normalize + upsample + mask, then fused CCL in the last-arriving
// block of each image. 128 blocks x 1024 threads = 2 blocks/image, each
// covering 112 rows (25088 px = 392 mask words, wave-uniform split).
// Mask words: agent-scope stores (cross-XCD visible within dispatch,
// validated round 1). Elected CCL runs at 16 waves (validated round 2).
// ~38 KB LDS.
// =====================================================================
__global__ __launch_bounds__(1024) void k23_heatmask(const float* __restrict__ heatPart,
                                                     float* __restrict__ heatOut,
                                                     unsigned long long* __restrict__ maskW,
                                                     unsigned* __restrict__ imgCnt,
                                                     float* __restrict__ coords) {
#pragma clang fp contract(off)
    // ---- phase A state
    __shared__ float raw[HW7];
    __shared__ float h7[HW7];
    __shared__ float s_mn, s_mx;
    __shared__ float wT[OUTW];      // fractional weight per output index
    __shared__ int   i0T[OUTW];     // low tap
    __shared__ int   i1T[OUTW];     // high tap
    __shared__ int   s_last;
    // ---- phase B (CCL) state
    __shared__ unsigned long long W[WPAD];
    __shared__ unsigned short runS[RCAP], runE[RCAP];
    __shared__ unsigned char nRuns[224];
    __shared__ unsigned parent[RCAP], cnt[RCAP];
    __shared__ unsigned rmin[RCAP], rmax[RCAP], cmin[RCAP], cmax[RCAP];
    __shared__ unsigned bestScore, bestRid;

    const int t = threadIdx.x;
    const int b = blockIdx.x;
    const int n = b >> 1, slice = b & 1;

    if (t < HW7) {
        float m = heatPart[(n * NGRP + 0) * HW7 + t];
#pragma unroll
        for (int g = 1; g < NGRP; ++g) m = fmaxf(m, heatPart[(n * NGRP + g) * HW7 + t]);
        raw[t] = m;
    }
    if (t < OUTW) {
        // EXACT reference op order: g = i/223 ; s = g*6 ; floor/clip ; w = s - i0
        float gx = (float)t / 223.0f;
        float xs = gx * 6.0f;
        int x0 = (int)floorf(xs); x0 = min(max(x0, 0), 6);
        i0T[t] = x0;
        i1T[t] = min(x0 + 1, 6);
        wT[t]  = xs - (float)x0;
    }
    __syncthreads();
    if (t == 0) {
        float mn = raw[0], mx = raw[0];
        for (int i = 1; i < HW7; ++i) { float v = raw[i]; mn = fminf(mn, v); mx = fmaxf(mx, v); }
        s_mn = mn; s_mx = mx;
    }
    __syncthreads();
    if (t < HW7) h7[t] = (raw[t] - s_mn) / (s_mx - s_mn);
    __syncthreads();

    const int pbase = slice * 25088;   // 112 rows * 224
    for (int k = 0; k < 25; ++k) {
        int pl = (k << 10) + t;
        if (pl < 25088) {              // boundary multiple of 64 -> wave-uniform
            int p = pbase + pl;
            int i = p / 224, j = p - i * 224;
            int x0 = i0T[i], x1 = i1T[i];
            int y0 = i0T[j], y1 = i1T[j];
            float wx = wT[i], wy = wT[j];
            float v00 = h7[x0 * 7 + y0], v01 = h7[x0 * 7 + y1];
            float v10 = h7[x1 * 7 + y0], v11 = h7[x1 * 7 + y1];
            float val = (1.0f - wx) * ((1.0f - wy) * v00 + wy * v01)
                      + wx * ((1.0f - wy) * v10 + wy * v11);
            heatOut[(size_t)n * NPIX + p] = val;
            unsigned long long bal = __ballot(val > THRESH);
            if ((t & 63) == 0) {
                // cross-XCD-visible within this dispatch (validated round 1)
                __hip_atomic_store(&maskW[(size_t)n * NWORDS + (p >> 6)], bal,
                                   __ATOMIC_RELAXED, __HIP_MEMORY_SCOPE_AGENT);
            }
        }
    }

    // ---- arrival: syncthreads drains this block's stores (compiler emits
    // s_waitcnt vmcnt(0) before s_barrier); ACQ_REL fetch_add orders them.
    __syncthreads();
    if (t == 0) {
        unsigned old = __hip_atomic_fetch_add(&imgCnt[n], 1u,
                                              __ATOMIC_ACQ_REL, __HIP_MEMORY_SCOPE_AGENT);
        s_last = (old == 1u);
    }
    __syncthreads();
    if (!s_last) return;              // block-uniform: safe w.r.t. later barriers

    // ================= phase B: CCL for image n (16 waves) =================
    if (t < NWORDS) W[t] = __hip_atomic_load(&maskW[(size_t)n * NWORDS + t],
                                             __ATOMIC_RELAXED, __HIP_MEMORY_SCOPE_AGENT);
    if (t >= NWORDS && t < WPAD) W[t] = 0ull;      // pad words: zero locally
    if (t < RCAP) {
        parent[t] = (unsigned)t; cnt[t] = 0u;
        rmin[t] = 0xFFFFFFFFu; rmax[t] = 0u; cmin[t] = 0xFFFFFFFFu; cmax[t] = 0u;
    }
    if (t == 0) { bestScore = 0u; bestRid = 0u; }
    __syncthreads();

    // ---- run extraction: one thread per row, bit-trick start/end finding
    if (t < 224) {
        const int r = t;
        const int bit0 = r * 224;
        const int w0 = bit0 >> 6, sh = bit0 & 63;
        unsigned long long rb[4];
#pragma unroll
        for (int q = 0; q < 4; ++q) {
            unsigned long long lo = W[w0 + q] >> sh;
            unsigned long long hi = sh ? (W[w0 + q + 1] << (64 - sh)) : 0ull;
            rb[q] = lo | hi;
        }
        rb[3] &= 0xFFFFFFFFull;   // keep bits 192..223 only

        unsigned long long st[4], en[4];
        unsigned long long carry = 0ull;
#pragma unroll
        for (int q = 0; q < 4; ++q) {
            unsigned long long shl = (rb[q] << 1) | carry;
            carry = rb[q] >> 63;
            st[q] = rb[q] & ~shl;                         // run starts
        }
#pragma unroll
        for (int q = 0; q < 4; ++q) {
            unsigned long long nxt = (q < 3) ? rb[q + 1] : 0ull;
            en[q] = rb[q] & ~((rb[q] >> 1) | (nxt << 63)); // run ends
        }
        int ns = 0;
#pragma unroll
        for (int q = 0; q < 4; ++q) {
            unsigned long long x = st[q];
            while (x) {
                int z = __builtin_ctzll(x); x &= x - 1;
                if (ns < MAXR) runS[r * MAXR + ns] = (unsigned short)(q * 64 + z);
                ns++;
            }
        }
        int ne = 0;
#pragma unroll
        for (int q = 0; q < 4; ++q) {
            unsigned long long x = en[q];
            while (x) {
                int z = __builtin_ctzll(x); x &= x - 1;
                if (ne < MAXR) runE[r * MAXR + ne] = (unsigned short)(q * 64 + z);
                ne++;
            }
        }
        nRuns[r] = (unsigned char)min(ns, MAXR);
    }
    __syncthreads();

    // ---- union runs overlapping (8-connectivity) with previous row.
    // Parallel over (row, run): 896 threads, each <=4 overlap tests.
    if (t >= MAXR && t < RCAP) {           // rows 1..223
        const int r = t >> 2, k = t & (MAXR - 1);
        if (k < (int)nRuns[r]) {
            const int nb = nRuns[r - 1];
            int s = runS[t], e = runE[t];
            for (int m = 0; m < nb; ++m) {
                int qid = (r - 1) * MAXR + m;
                int s2 = runS[qid], e2 = runE[qid];
                if (s2 <= e + 1 && e2 >= s - 1) uf_merge(parent, (unsigned)t, (unsigned)qid);
            }
        }
    }
    __syncthreads();

    // ---- accumulate sizes + per-component bbox (1 iteration: RCAP < 1024)
    if (t < RCAP) {
        int r = t >> 2, k = t & (MAXR - 1);
        if (k < (int)nRuns[r]) {
            int s = runS[t], e = runE[t];
            unsigned root = uf_find(parent, (unsigned)t);
            atomicAdd(&cnt[root], (unsigned)(e - s + 1));
            atomicMin(&rmin[root], (unsigned)r);
            atomicMax(&rmax[root], (unsigned)r);
            atomicMin(&cmin[root], (unsigned)s);
            atomicMax(&cmax[root], (unsigned)e);
        }
    }
    __syncthreads();

    // ---- select: max count, tie -> min reference label (= min pixel index)
    if (t < RCAP) {
        unsigned c = cnt[t];
        if (c > 0u) {
            unsigned label = (unsigned)((t >> 2) * 224 + (int)runS[t]); // root = min (row,start)
            unsigned score = (c << 16) | (65535u - label);
            atomicMax(&bestScore, score);
        }
    }
    __syncthreads();
    if (t < RCAP) {
        unsigned c = cnt[t];
        if (c > 0u) {
            unsigned label = (unsigned)((t >> 2) * 224 + (int)runS[t]);
            unsigned score = (c << 16) | (65535u - label);
            if (score == bestScore) bestRid = (unsigned)t;  // unique writer
        }
    }
    __syncthreads();

    if (t == 0) {
        int xmin, xmax, ymin, ymax;
        if (bestScore == 0u) {           // empty mask -> reference fallback
            xmin = 0; ymin = 0; xmax = 223; ymax = 223;
        } else {
            unsigned rb_ = bestRid;
            xmin = (int)rmin[rb_]; xmax = (int)rmax[rb_];
            ymin = (int)cmin[rb_]; ymax = (int)cmax[rb_];
        }
        coords[n * 4 + 0] = (float)ymin;  // torch coord order [ymin,xmin,ymax,xmax]
        coords[n * 4 + 1] = (float)xmin;
        coords[n * 4 + 2] = (float)ymax;
        coords[n * 4 + 3] = (float)xmax;
    }
}

// =====================================================================
// K4: crop + bilinear resize. 4 pixels per thread (same output row:
// 224 % 4 == 0), so x-taps/wx are computed once per thread; stores are
// dwordx4. 3136 blocks = 49 per image. Memory-bound (~77 MB).
// =====================================================================
__global__ __launch_bounds__(256) void k4_crop(const float* __restrict__ X,
                                               const float* __restrict__ coords,
                                               float* __restrict__ out) {
#pragma clang fp contract(off)
    const int t = threadIdx.x;
    const int b = blockIdx.x;
    const int n = b / 49;                // uniform per block -> coords loads scalarize
    const int p4 = ((b % 49) * 256 + t) * 4;
    const int oi = p4 / 224, oj = p4 - oi * 224;   // oj..oj+3 in same row

    int ymin = (int)coords[n * 4 + 0];
    int xmin = (int)coords[n * 4 + 1];
    int ymax = (int)coords[n * 4 + 2];
    int xmax = (int)coords[n * 4 + 3];
    int Lx = max(xmax - xmin, 1);
    int Ly = max(ymax - ymin, 1);

    // x (row) taps: identical for all 4 pixels of this thread
    float gx = (float)oi / 223.0f;
    float xs = (float)xmin + gx * (float)(Lx - 1);
    int x0 = (int)floorf(xs); x0 = min(max(x0, 0), 223); int x1 = min(x0 + 1, 223);
    float wx = xs - (float)x0;

    int   y0q[4], y1q[4];
    float wyq[4];
#pragma unroll
    for (int q = 0; q < 4; ++q) {
        float gy = (float)(oj + q) / 223.0f;
        float ys = (float)ymin + gy * (float)(Ly - 1);
        int y0 = (int)floorf(ys); y0 = min(max(y0, 0), 223);
        y0q[q] = y0; y1q[q] = min(y0 + 1, 223);
        wyq[q] = ys - (float)y0;
    }

    const float* img = X + (size_t)n * 150528;
    float* obase = out + (size_t)n * 150528 + p4;
#pragma unroll
    for (int ch = 0; ch < 3; ++ch) {
        const float* rt = img + ch * NPIX + x0 * 224;
        const float* rb = img + ch * NPIX + x1 * 224;
        float r[4];
#pragma unroll
        for (int q = 0; q < 4; ++q) {
            float v00 = rt[y0q[q]], v01 = rt[y1q[q]];
            float v10 = rb[y0q[q]], v11 = rb[y1q[q]];
            r[q] = (1.0f - wx) * ((1.0f - wyq[q]) * v00 + wyq[q] * v01)
                 + wx * ((1.0f - wyq[q]) * v10 + wyq[q] * v11);
        }
        *reinterpret_cast<float4*>(obase + (size_t)ch * NPIX) =
            make_float4(r[0], r[1], r[2], r[3]);
    }
}

// =====================================================================
extern "C" void kernel_launch(void* const* d_in, const int* in_sizes, int n_in,
                              void* d_out, int out_size, void* d_ws, size_t ws_size,
                              hipStream_t stream) {
    (void)in_sizes; (void)n_in; (void)out_size; (void)d_ws; (void)ws_size;
    const float* X = (const float*)d_in[0];   // (64,3,224,224)
    const float* F = (const float*)d_in[1];   // (64,2048,7,7)
    float* out = (float*)d_out;

    float* heatPart = (float*)d_out;                                          // scratch in crop region
    unsigned long long* maskW = (unsigned long long*)((char*)d_out + MASKW_BYTE_OFF);
    unsigned* imgCnt = (unsigned*)((char*)d_out + CNT_BYTE_OFF);
    float* heatOut = out + HEAT_OFF;
    float* coords  = out + COORD_OFF;

    k1_heat     <<<dim3(1024), dim3(256),  0, stream>>>(F, heatPart, imgCnt);
    k23_heatmask<<<dim3(128),  dim3(1024), 0, stream>>>(heatPart, heatOut, maskW, imgCnt, coords);
    k4_crop     <<<dim3(3136), dim3(256),  0, stream>>>(X, coords, out);
}